// Round 1
// baseline (130.998 us; speedup 1.0000x reference)
//
#include <hip/hip_runtime.h>
#include <math.h>

// Non-local attention: X [8, 64, 64, 64] fp32.
// Per batch b: Q=K=V = X_b^T  [S=4096, D=64];  out = softmax(Q K^T) V, stored [b][c][s].
//
// R11: LDS-free inner loop. Key insight: the S-MFMA output fragment (lane (l15,quad)
// holds score(q=l15, key=16mt+4quad+r)) is EXACTLY the A-fragment layout of
// v_mfma_f32_16x16x16_bf16 (lane holds A[row=l15][k=4quad+r]). So PV done as K=16
// MFMAs per 16-key block consumes the exp'd scores with ZERO cross-lane movement:
// no P LDS write/read, no lgkmcnt stall, no bank conflicts. The matching V^T
// B-fragment (4 keys/lane) is loaded straight from the existing Vf layout via a
// per-lane permuted address (each 8B-load instruction still covers one contiguous
// 512B region = 4 full cache lines). K fragments are register double-buffered
// (unroll-by-2, named buffers); V issued at iter top, consumed a phase later.
// s_setprio(1) wraps the MFMA clusters. Split-K x4, 2 waves x 32 Q rows, raw
// v_exp_f32 softmax with the fixed Cauchy-Schwarz bound folded into the MFMA C-init.
//
// Kf[b][tile][mt][ks][lane]: scaled bf16, lane(=quad*16+l15) holds
//   XbfT_scaled[tile*32+mt*16+l15][quad*8+32*ks .. +8]   (also serves Q fragments)
// Vf[b][tile][ct][kq][l15][s]: unscaled bf16, short index
//   tile*2048 + (ct*64+kq*16+l15)*8 + s  =  XbfT[tile*32+kq*8+s][16ct+l15]

#define SEQ 4096
#define DIM 64
#define LDB 72
#define LDO 68
#define LDS2 68
#define QSCALE 1.2011224087864498f   // sqrt(log2(e))

typedef __attribute__((ext_vector_type(8))) short  short8;
typedef __attribute__((ext_vector_type(4))) short  bhalf4;
typedef __attribute__((ext_vector_type(4))) float  f32x4;

__device__ __forceinline__ unsigned short f2bf(float f) {
    union { float f; unsigned int u; } x; x.f = f;
    unsigned int u = x.u + 0x7FFFu + ((x.u >> 16) & 1u);
    return (unsigned short)(u >> 16);
}
__device__ __forceinline__ float bf2f(unsigned short h) {
    union { unsigned int u; float f; } x; x.u = ((unsigned int)h) << 16; return x.f;
}
__device__ __forceinline__ float fast_exp2(float x) {
#if __has_builtin(__builtin_amdgcn_exp2f)
    return __builtin_amdgcn_exp2f(x);
#else
    float r;
    asm("v_exp_f32 %0, %1\n\ts_nop 0" : "=v"(r) : "v"(x));
    return r;
#endif
}
__device__ __forceinline__ float fast_rcp(float x) {
#if __has_builtin(__builtin_amdgcn_rcpf)
    return __builtin_amdgcn_rcpf(x);
#else
    return 1.f / x;
#endif
}

// K=16 bf16 MFMA for the PV step (A-frag layout == S-output layout, see header).
__device__ __forceinline__ f32x4 mfma_pv16(bhalf4 a, bhalf4 b, f32x4 c) {
#if __has_builtin(__builtin_amdgcn_mfma_f32_16x16x16bf16_1k)
    return __builtin_amdgcn_mfma_f32_16x16x16bf16_1k(a, b, c, 0, 0, 0);
#elif __has_builtin(__builtin_amdgcn_mfma_f32_16x16x16_bf16_1k)
    return __builtin_amdgcn_mfma_f32_16x16x16_bf16_1k(a, b, c, 0, 0, 0);
#else
    f32x4 d;
    asm("v_mfma_f32_16x16x16_bf16 %0, %1, %2, %3"
        : "=&v"(d) : "v"(a), "v"(b), "v"(c));
    return d;
#endif
}

// ---------------- prepass: fragment-order bf16 arrays + scaled norms + max partials ----
__global__ __launch_bounds__(256) void prepass4(const float* __restrict__ X,
                                                unsigned short* __restrict__ Kf,
                                                unsigned short* __restrict__ Vf,
                                                float* __restrict__ Norms,
                                                float* __restrict__ MaxPart) {
    __shared__ __align__(16) unsigned short sT[64 * LDS2];    // scaled [m][c]
    __shared__ __align__(16) unsigned short sVu[64 * LDS2];   // unscaled [c][m]
    __shared__ float sRed[4];
    const int b = blockIdx.y, m0 = blockIdx.x * 64;
    const float* Xb = X + (size_t)b * DIM * SEQ;
    const int t = threadIdx.x, w = t >> 6;
    const int mw = t & 15, cg = t >> 4;

    #pragma unroll
    for (int cr = 0; cr < 4; ++cr) {
        const int c = cg * 4 + cr;
        const f32x4 v = *(const f32x4*)(Xb + (size_t)c * SEQ + m0 + 4 * mw);
        *(ushort4*)(sVu + c * LDS2 + 4 * mw) =
            make_ushort4(f2bf(v.x), f2bf(v.y), f2bf(v.z), f2bf(v.w));
        sT[(4 * mw + 0) * LDS2 + c] = f2bf(v.x * QSCALE);
        sT[(4 * mw + 1) * LDS2 + c] = f2bf(v.y * QSCALE);
        sT[(4 * mw + 2) * LDS2 + c] = f2bf(v.z * QSCALE);
        sT[(4 * mw + 3) * LDS2 + c] = f2bf(v.w * QSCALE);
    }
    __syncthreads();
    const int m = t >> 2, ck = t & 3;   // m: key row (for Kf) AND chan row (for Vf)

    // ---- Kf: row m, dim-chunks 2ck and 2ck+1 ----
    const short8 a0 = *(const short8*)(sT + m * LDS2 + ck * 16);
    const short8 a1 = *(const short8*)(sT + m * LDS2 + ck * 16 + 8);
    {
        const size_t base = (size_t)b * 262144 + (size_t)(m0 >> 5) * 2048;  // shorts
        #pragma unroll
        for (int j = 0; j < 2; ++j) {
            const int chunk = 2 * ck + j;
            const int tile = m >> 5, mt = (m >> 4) & 1;
            const int quad = chunk & 3, ks = chunk >> 2;
            const size_t off = base + (size_t)(tile * 4 + mt * 2 + ks) * 512
                                    + (size_t)(quad * 16 + (m & 15)) * 8;
            *(short8*)(Kf + off) = j ? a1 : a0;
        }
    }
    // ---- scaled row norm (from a0/a1), exact C-S bound on scaled scores ----
    float s = 0.f;
    #pragma unroll
    for (int i = 0; i < 8; ++i) {
        const float f0 = bf2f((unsigned short)a0[i]);
        const float f1 = bf2f((unsigned short)a1[i]);
        s += f0 * f0 + f1 * f1;
    }
    s += __shfl_xor(s, 1);
    s += __shfl_xor(s, 2);
    const float nm = sqrtf(s);
    if (ck == 0) Norms[(size_t)b * SEQ + m0 + m] = nm;

    // ---- Vf: chan m, key-chunks 2ck and 2ck+1 ----
    const short8 v0 = *(const short8*)(sVu + m * LDS2 + ck * 16);
    const short8 v1 = *(const short8*)(sVu + m * LDS2 + ck * 16 + 8);
    {
        const size_t base = (size_t)b * 262144;
        #pragma unroll
        for (int j = 0; j < 2; ++j) {
            const int chunk = 2 * ck + j;
            const int tile = chunk >> 2, quad = chunk & 3;
            const size_t off = base + (size_t)((m0 >> 5) + tile) * 2048
                                    + (size_t)((m >> 4) * 64 + quad * 16 + (m & 15)) * 8;
            *(short8*)(Vf + off) = j ? v1 : v0;
        }
    }

    float mx = nm;
    #pragma unroll
    for (int d = 4; d < 64; d <<= 1) mx = fmaxf(mx, __shfl_xor(mx, d));
    if ((t & 63) == 0) sRed[w] = mx;
    __syncthreads();
    if (t == 0)
        MaxPart[b * 64 + blockIdx.x] =
            fmaxf(fmaxf(sRed[0], sRed[1]), fmaxf(sRed[2], sRed[3]));
}

// ---- per-iteration macros for the flash loop (kp/vp16/qf/cin/acc_o/lp4 in scope) ----
#define LOADK(DST)                                                                 \
    {                                                                              \
        _Pragma("unroll")                                                          \
        for (int mt_ = 0; mt_ < 2; ++mt_) {                                        \
            _Pragma("unroll")                                                      \
            for (int ks_ = 0; ks_ < 2; ++ks_)                                      \
                DST[mt_][ks_] = *(const short8*)(kp + (mt_ * 2 + ks_) * 512);      \
        }                                                                          \
    }

#define LOADV(DST)                                                                 \
    {                                                                              \
        _Pragma("unroll")                                                          \
        for (int mt_ = 0; mt_ < 2; ++mt_) {                                        \
            _Pragma("unroll")                                                      \
            for (int ct_ = 0; ct_ < 4; ++ct_)                                      \
                DST[mt_][ct_] = *(const bhalf4*)(vp16 + mt_ * 256 + ct_ * 512);    \
        }                                                                          \
    }

#define ATTN_STEP(KF, VF)                                                          \
    {                                                                              \
        f32x4 a_[2][2];                                                            \
        __builtin_amdgcn_s_setprio(1);                                             \
        _Pragma("unroll")                                                          \
        for (int qt_ = 0; qt_ < 2; ++qt_) {                                        \
            _Pragma("unroll")                                                      \
            for (int mt_ = 0; mt_ < 2; ++mt_) {                                    \
                f32x4 s_ = cin[qt_];                                               \
                s_ = __builtin_amdgcn_mfma_f32_16x16x32_bf16(KF[mt_][0], qf[qt_][0], s_, 0, 0, 0); \
                s_ = __builtin_amdgcn_mfma_f32_16x16x32_bf16(KF[mt_][1], qf[qt_][1], s_, 0, 0, 0); \
                a_[qt_][mt_] = s_;                                                 \
            }                                                                      \
        }                                                                          \
        __builtin_amdgcn_s_setprio(0);                                             \
        bhalf4 pa_[2][2];                                                          \
        _Pragma("unroll")                                                          \
        for (int qt_ = 0; qt_ < 2; ++qt_) {                                        \
            _Pragma("unroll")                                                      \
            for (int mt_ = 0; mt_ < 2; ++mt_) {                                    \
                const float p0_ = fast_exp2(a_[qt_][mt_][0]);                      \
                const float p1_ = fast_exp2(a_[qt_][mt_][1]);                      \
                const float p2_ = fast_exp2(a_[qt_][mt_][2]);                      \
                const float p3_ = fast_exp2(a_[qt_][mt_][3]);                      \
                lp4[qt_] += (f32x4){p0_, p1_, p2_, p3_};                           \
                union { unsigned u[2]; bhalf4 v; } cv_;                            \
                cv_.u[0] = __builtin_amdgcn_perm(__float_as_uint(p1_), __float_as_uint(p0_), 0x07060302u); \
                cv_.u[1] = __builtin_amdgcn_perm(__float_as_uint(p3_), __float_as_uint(p2_), 0x07060302u); \
                pa_[qt_][mt_] = cv_.v;                                             \
            }                                                                      \
        }                                                                          \
        __builtin_amdgcn_s_setprio(1);                                             \
        _Pragma("unroll")                                                          \
        for (int qt_ = 0; qt_ < 2; ++qt_) {                                        \
            _Pragma("unroll")                                                      \
            for (int mt_ = 0; mt_ < 2; ++mt_) {                                    \
                _Pragma("unroll")                                                  \
                for (int ct_ = 0; ct_ < 4; ++ct_)                                  \
                    acc_o[qt_][ct_] = mfma_pv16(pa_[qt_][mt_], VF[mt_][ct_], acc_o[qt_][ct_]); \
            }                                                                      \
        }                                                                          \
        __builtin_amdgcn_s_setprio(0);                                             \
    }

// BN=32 flash kernel, 2 waves x 32 Q rows, split-K x4. Fragment-order global K/V,
// LDS-free inner loop (P stays in registers; PV uses K=16 MFMAs).
template <bool PARTIAL>
__global__ __launch_bounds__(128) void attn_split4(const unsigned short* __restrict__ Kf,
                                                   const unsigned short* __restrict__ Vf,
                                                   const float* __restrict__ Norms,
                                                   const float* __restrict__ MaxPart,
                                                   unsigned short* __restrict__ Obf,  // PARTIAL
                                                   float* __restrict__ Lbase,         // PARTIAL
                                                   float* __restrict__ Out,           // !PARTIAL
                                                   int niter) {
    __shared__ __align__(16) float sO[64 * LDO];   // epilogue staging only (17408 B)

    const int tid  = threadIdx.x;
    const int lane = tid & 63;
    const int w    = tid >> 6;
    const int l15  = lane & 15;
    const int quad = lane >> 4;

    const int b   = blockIdx.y;
    const int s0  = blockIdx.x * 64;
    const int h   = blockIdx.z;
    const int kt0 = h * niter;
    const unsigned short* Kfb = Kf + (size_t)b * 262144;
    const unsigned short* Vfb = Vf + (size_t)b * 262144;

    float mxn = MaxPart[b * 64 + lane];
    #pragma unroll
    for (int d = 1; d < 64; d <<= 1) mxn = fmaxf(mxn, __shfl_xor(mxn, d));

    // Q frags from Kf (scaled): row = s0+32w+16qt+l15 -> tile=(s0+32w)>>5, mt=qt
    short8 qf[2][2];
    f32x4 cin[2];
    const int qtile = (s0 + 32 * w) >> 5;
    #pragma unroll
    for (int qt = 0; qt < 2; ++qt) {
        #pragma unroll
        for (int ks = 0; ks < 2; ++ks)
            qf[qt][ks] = *(const short8*)(Kfb + (size_t)(qtile * 4 + qt * 2 + ks) * 512 + lane * 8);
        const float mrow = Norms[(size_t)b * SEQ + s0 + 32 * w + 16 * qt + l15] * mxn;
        cin[qt] = (f32x4){-mrow, -mrow, -mrow, -mrow};
    }

    f32x4 acc_o[2][4];
    #pragma unroll
    for (int qt = 0; qt < 2; ++qt)
        #pragma unroll
        for (int ct = 0; ct < 4; ++ct) acc_o[qt][ct] = (f32x4){0.f, 0.f, 0.f, 0.f};
    f32x4 lp4[2];
    lp4[0] = (f32x4){0.f, 0.f, 0.f, 0.f};
    lp4[1] = (f32x4){0.f, 0.f, 0.f, 0.f};

    // ---- fragment stream pointers ----
    // K: lane-contiguous 1KB per 16B-load (unchanged layout).
    const unsigned short* kp = Kfb + (size_t)kt0 * 2048 + lane * 8;
    // V as K=16 B-frags: lane (l15,quad) needs V^T[c=16ct+l15][key=16mt+4quad .. +4]
    //   = Vf shorts at tile*2048 + (ct*64 + (2mt+(quad>>1))*16 + l15)*8 + 4*(quad&1).
    // Per 8B-load instruction the wave covers one contiguous 512B region (permuted).
    const unsigned short* vp16 = Vfb + (size_t)kt0 * 2048
                               + (size_t)((((quad >> 1) * 16 + l15) * 8) + 4 * (quad & 1));

    short8 kA[2][2], kB[2][2];
    LOADK(kA);
    kp += 2048;

    for (int it = 0; it < niter; it += 2) {
        bhalf4 vfA[2][4];
        LOADV(vfA); vp16 += 2048;
        LOADK(kB);  kp += 2048;          // prefetch K for iter it+1
        ATTN_STEP(kA, vfA);

        bhalf4 vfB[2][4];
        LOADV(vfB); vp16 += 2048;
        LOADK(kA);  kp += 2048;          // prefetch K for iter it+2; on the final pair this
                                         // over-reads <=2 tiles past the slab end -- still
                                         // inside d_ws (Vf/Norms regions), values unused.
        ATTN_STEP(kB, vfB);
    }

    float lp[2];
    #pragma unroll
    for (int qt = 0; qt < 2; ++qt) {
        lp[qt] = (lp4[qt][0] + lp4[qt][1]) + (lp4[qt][2] + lp4[qt][3]);
        lp[qt] += __shfl_xor(lp[qt], 16);
        lp[qt] += __shfl_xor(lp[qt], 32);
    }

    if (PARTIAL) {
        if (quad == 0) {
            #pragma unroll
            for (int qt = 0; qt < 2; ++qt)
                (Lbase + (size_t)h * 8 * SEQ)[(size_t)b * SEQ + s0 + 32 * w + 16 * qt + l15] = lp[qt];
        }
    } else {
        #pragma unroll
        for (int qt = 0; qt < 2; ++qt) {
            float inv[4];
            #pragma unroll
            for (int r = 0; r < 4; ++r) inv[r] = fast_rcp(__shfl(lp[qt], 4 * quad + r));
            #pragma unroll
            for (int ct = 0; ct < 4; ++ct)
                #pragma unroll
                for (int r = 0; r < 4; ++r) acc_o[qt][ct][r] *= inv[r];
        }
    }

    #pragma unroll
    for (int qt = 0; qt < 2; ++qt)
        #pragma unroll
        for (int ct = 0; ct < 4; ++ct) {
            const int c = 16 * ct + l15;
            #pragma unroll
            for (int r = 0; r < 4; ++r)
                sO[c * LDO + 32 * w + 16 * qt + 4 * quad + r] = acc_o[qt][ct][r];
        }
    __syncthreads();
    const int mw = tid & 15, cg = tid >> 4;
    if (PARTIAL) {
        unsigned short* Op = Obf + (size_t)h * 8 * DIM * SEQ;
        #pragma unroll
        for (int cc = 0; cc < 8; ++cc) {
            const int c = cg + 8 * cc;
            const f32x4 v = *(const f32x4*)(sO + c * LDO + 4 * mw);
            *(ushort4*)(Op + ((size_t)b * DIM + c) * SEQ + s0 + 4 * mw) =
                make_ushort4(f2bf(v.x), f2bf(v.y), f2bf(v.z), f2bf(v.w));
        }
    } else {
        #pragma unroll
        for (int cc = 0; cc < 8; ++cc) {
            const int c = cg + 8 * cc;
            const f32x4 v = *(const f32x4*)(sO + c * LDO + 4 * mw);
            *(f32x4*)(Out + ((size_t)b * DIM + c) * SEQ + s0 + 4 * mw) = v;
        }
    }
}

__global__ __launch_bounds__(256) void combine4(const unsigned short* __restrict__ Obf,
                                                const float* __restrict__ Lp,
                                                float* __restrict__ Out) {
    const int gid = blockIdx.x * 256 + threadIdx.x;
    const size_t base = (size_t)gid * 4;
    const int s = (int)(base & 4095);
    const int b = (int)(base >> 18);
    f32x4 os = (f32x4){0.f, 0.f, 0.f, 0.f};
    f32x4 ls = (f32x4){0.f, 0.f, 0.f, 0.f};
    #pragma unroll
    for (int h = 0; h < 4; ++h) {
        const ushort4 o = *(const ushort4*)(Obf + (size_t)h * 2097152 + base);
        os[0] += bf2f(o.x); os[1] += bf2f(o.y); os[2] += bf2f(o.z); os[3] += bf2f(o.w);
        const f32x4 l = *(const f32x4*)(Lp + (size_t)h * 8 * SEQ + b * SEQ + s);
        #pragma unroll
        for (int i = 0; i < 4; ++i) ls[i] += l[i];
    }
    f32x4 o;
    #pragma unroll
    for (int i = 0; i < 4; ++i) o[i] = os[i] / ls[i];
    *(f32x4*)(Out + base) = o;
}

__global__ __launch_bounds__(256, 2) void attn_fallback(const float* __restrict__ X,
                                                        float* __restrict__ Out) {
    __shared__ __align__(16) unsigned char smem[27648];
    unsigned short* sK = (unsigned short*)smem;
    unsigned short* sV = (unsigned short*)(smem + 9216);
    unsigned short* sP = (unsigned short*)(smem + 18432);
    float*          sO = (float*)smem;
    const int tid  = threadIdx.x;
    const int lane = tid & 63;
    const int w    = tid >> 6;
    const int l15  = lane & 15;
    const int quad = lane >> 4;
    const int b  = blockIdx.y;
    const int s0 = blockIdx.x * 64;
    const float* Xb = X + (size_t)b * DIM * SEQ;
    const int mgrp = tid & 15;
    const int c0   = tid >> 4;

    for (int cc = 0; cc < 4; ++cc) {
        int c = c0 + 16 * cc;
        const f32x4 v = *(const f32x4*)(Xb + (size_t)c * SEQ + s0 + 4 * mgrp);
        sK[(4 * mgrp + 0) * LDB + c] = f2bf(v.x);
        sK[(4 * mgrp + 1) * LDB + c] = f2bf(v.y);
        sK[(4 * mgrp + 2) * LDB + c] = f2bf(v.z);
        sK[(4 * mgrp + 3) * LDB + c] = f2bf(v.w);
    }
    __syncthreads();
    short8 qf0, qf1;
    {
        const int row = 16 * w + l15;
        qf0 = *(const short8*)(sK + row * LDB + quad * 8);
        qf1 = *(const short8*)(sK + row * LDB + 32 + quad * 8);
    }
    __syncthreads();
    f32x4 acc_o[4];
    for (int ct = 0; ct < 4; ++ct) acc_o[ct] = (f32x4){0.f, 0.f, 0.f, 0.f};
    float m_i[4] = {-1e30f, -1e30f, -1e30f, -1e30f};
    float l_i[4] = {0.f, 0.f, 0.f, 0.f};
    for (int kt = 0; kt < SEQ / 64; ++kt) {
        const int m0 = kt * 64;
        for (int cc = 0; cc < 4; ++cc) {
            int c = c0 + 16 * cc;
            const f32x4 v = *(const f32x4*)(Xb + (size_t)c * SEQ + m0 + 4 * mgrp);
            unsigned short h0 = f2bf(v.x), h1 = f2bf(v.y), h2 = f2bf(v.z), h3 = f2bf(v.w);
            *(ushort4*)(sV + c * LDB + 4 * mgrp) = make_ushort4(h0, h1, h2, h3);
            sK[(4 * mgrp + 0) * LDB + c] = h0;
            sK[(4 * mgrp + 1) * LDB + c] = h1;
            sK[(4 * mgrp + 2) * LDB + c] = h2;
            sK[(4 * mgrp + 3) * LDB + c] = h3;
        }
        __syncthreads();
        short8 vf[2][4];
        for (int ks = 0; ks < 2; ++ks)
            for (int ct = 0; ct < 4; ++ct)
                vf[ks][ct] = *(const short8*)(sV + (16 * ct + l15) * LDB + ks * 32 + quad * 8);
        f32x4 acc_s[4];
        for (int mt = 0; mt < 4; ++mt) {
            const int row = 16 * mt + l15;
            const short8 kf0 = *(const short8*)(sK + row * LDB + quad * 8);
            const short8 kf1 = *(const short8*)(sK + row * LDB + 32 + quad * 8);
            f32x4 a = (f32x4){0.f, 0.f, 0.f, 0.f};
            a = __builtin_amdgcn_mfma_f32_16x16x32_bf16(qf0, kf0, a, 0, 0, 0);
            a = __builtin_amdgcn_mfma_f32_16x16x32_bf16(qf1, kf1, a, 0, 0, 0);
            acc_s[mt] = a;
        }
        float alpha[4];
        for (int r = 0; r < 4; ++r) {
            float mx = fmaxf(fmaxf(acc_s[0][r], acc_s[1][r]), fmaxf(acc_s[2][r], acc_s[3][r]));
            mx = fmaxf(mx, __shfl_xor(mx, 1));
            mx = fmaxf(mx, __shfl_xor(mx, 2));
            mx = fmaxf(mx, __shfl_xor(mx, 4));
            mx = fmaxf(mx, __shfl_xor(mx, 8));
            const float mnew = fmaxf(m_i[r], mx);
            alpha[r] = __expf(m_i[r] - mnew);
            m_i[r] = mnew;
        }
        float rowsum[4] = {0.f, 0.f, 0.f, 0.f};
        unsigned short pb[4][4];
        for (int mt = 0; mt < 4; ++mt)
            for (int r = 0; r < 4; ++r) {
                const float p = __expf(acc_s[mt][r] - m_i[r]);
                rowsum[r] += p;
                pb[mt][r] = f2bf(p);
            }
        for (int r = 0; r < 4; ++r) {
            float s = rowsum[r];
            s += __shfl_xor(s, 1);
            s += __shfl_xor(s, 2);
            s += __shfl_xor(s, 4);
            s += __shfl_xor(s, 8);
            l_i[r] = alpha[r] * l_i[r] + s;
        }
        for (int ct = 0; ct < 4; ++ct)
            for (int r = 0; r < 4; ++r)
                acc_o[ct][r] *= alpha[r];
        for (int mt = 0; mt < 4; ++mt)
            for (int r = 0; r < 4; ++r)
                sP[(16 * w + quad * 4 + r) * LDB + l15 + 16 * mt] = pb[mt][r];
        __syncthreads();
        const short8 pf0 = *(const short8*)(sP + (16 * w + l15) * LDB + quad * 8);
        const short8 pf1 = *(const short8*)(sP + (16 * w + l15) * LDB + 32 + quad * 8);
        for (int ct = 0; ct < 4; ++ct) {
            acc_o[ct] = __builtin_amdgcn_mfma_f32_16x16x32_bf16(pf0, vf[0][ct], acc_o[ct], 0, 0, 0);
            acc_o[ct] = __builtin_amdgcn_mfma_f32_16x16x32_bf16(pf1, vf[1][ct], acc_o[ct], 0, 0, 0);
        }
    }
    float inv[4];
    for (int r = 0; r < 4; ++r) inv[r] = 1.f / l_i[r];
    for (int ct = 0; ct < 4; ++ct) {
        const int c = 16 * ct + l15;
        for (int r = 0; r < 4; ++r)
            sO[c * LDO + 16 * w + quad * 4 + r] = acc_o[ct][r] * inv[r];
    }
    __syncthreads();
    for (int cc = 0; cc < 4; ++cc) {
        const int c = c0 + 16 * cc;
        const f32x4 v = *(const f32x4*)(sO + c * LDO + 4 * mgrp);
        *(f32x4*)(Out + (size_t)b * DIM * SEQ + (size_t)c * SEQ + s0 + 4 * mgrp) = v;
    }
}

extern "C" void kernel_launch(void* const* d_in, const int* in_sizes, int n_in,
                              void* d_out, int out_size, void* d_ws, size_t ws_size,
                              hipStream_t stream) {
    const float* X = (const float*)d_in[0];
    float* Out = (float*)d_out;
    const size_t elems = (size_t)8 * SEQ * DIM;               // 2M
    const size_t offVf    = elems * 2;                        // Kf 4MB
    const size_t offNorms = offVf + elems * 2;                // Vf 4MB -> 8MB
    const size_t offMaxP  = offNorms + (size_t)8 * SEQ * 4;   // +128KB
    const size_t offObf   = offMaxP + 8 * 64 * 4;             // +2KB
    const size_t offLp    = offObf + 4 * elems * 2;           // +16MB (4 bf16 slabs)
    const size_t need     = offLp + 4 * (size_t)8 * SEQ * 4;  // ~24.64MB (proven budget)

    if (ws_size >= need) {
        unsigned short* Kf = (unsigned short*)d_ws;
        unsigned short* Vf = (unsigned short*)((char*)d_ws + offVf);
        float* Norms   = (float*)((char*)d_ws + offNorms);
        float* MaxPart = (float*)((char*)d_ws + offMaxP);
        unsigned short* Obf = (unsigned short*)((char*)d_ws + offObf);
        float* Lp = (float*)((char*)d_ws + offLp);
        prepass4<<<dim3(64, 8), 256, 0, stream>>>(X, Kf, Vf, Norms, MaxPart);
        attn_split4<true><<<dim3(64, 8, 4), 128, 0, stream>>>(Kf, Vf, Norms, MaxPart,
                                                              Obf, Lp, nullptr, 32);
        combine4<<<(int)(elems / 1024), 256, 0, stream>>>(Obf, Lp, Out);
    } else {
        attn_fallback<<<dim3(64, 8), 256, 0, stream>>>(X, Out);
    }
}

// Round 2
// 118.539 us; speedup vs baseline: 1.1051x; 1.1051x over previous
//
#include <hip/hip_runtime.h>
#include <math.h>

// Non-local attention: X [8, 64, 64, 64] fp32.
// Per batch b: Q=K=V = X_b^T  [S=4096, D=64];  out = softmax(Q K^T) V, stored [b][c][s].
//
// R12: zero-movement P at K=32. MFMA contracts over physical k-slots; A and B may use
// any shared k-slot<->key bijection. We pick  k-slot q*8+j  <->  key 16*(j>>2)+4q+(j&3).
// Then the PV A-fragment for lane (l15,q) is exactly the lane's OWN 8 exp'd scores
// (mt0 r0..3 ++ mt1 r0..3, already bf16-packed) -- no LDS, no shuffles -- and the PV
// B-fragment is V stored in that permuted key order, which the prepass lays out so each
// fragment is one lane-contiguous 16B load (4 x 1KB coalesced loads per tile).
// This keeps R10's MFMA count (16 x K=32 per iter) with R11's LDS-free P path.
// K register double-buffered one tile ahead; V loaded at iter top, consumed after
// S+exp. s_setprio(1) around MFMA clusters. Split-K x4, 2 waves x 32 Q rows, raw
// v_exp_f32 softmax with the fixed Cauchy-Schwarz bound folded into the MFMA C-init.
//
// Kf[b][tile][mt][ks][lane]: scaled bf16, lane(=quad*16+l15) holds
//   XbfT_scaled[tile*32+mt*16+l15][quad*8+32*ks .. +8]   (also serves Q fragments)
// Vf[b][tile][ct][lane][j]: unscaled bf16, element j at lane (l15,q) holds
//   XbfT[tile*32 + 16*(j>>2) + 4*q + (j&3)][16*ct + l15]   (permuted B-frag order)

#define SEQ 4096
#define DIM 64
#define LDB 72
#define LDO 68
#define LDS2 68
#define QSCALE 1.2011224087864498f   // sqrt(log2(e))

typedef __attribute__((ext_vector_type(8))) short  short8;
typedef __attribute__((ext_vector_type(4))) float  f32x4;

__device__ __forceinline__ unsigned short f2bf(float f) {
    union { float f; unsigned int u; } x; x.f = f;
    unsigned int u = x.u + 0x7FFFu + ((x.u >> 16) & 1u);
    return (unsigned short)(u >> 16);
}
__device__ __forceinline__ float bf2f(unsigned short h) {
    union { unsigned int u; float f; } x; x.u = ((unsigned int)h) << 16; return x.f;
}
__device__ __forceinline__ float fast_exp2(float x) {
#if __has_builtin(__builtin_amdgcn_exp2f)
    return __builtin_amdgcn_exp2f(x);
#else
    float r;
    asm("v_exp_f32 %0, %1\n\ts_nop 0" : "=v"(r) : "v"(x));
    return r;
#endif
}
__device__ __forceinline__ float fast_rcp(float x) {
#if __has_builtin(__builtin_amdgcn_rcpf)
    return __builtin_amdgcn_rcpf(x);
#else
    return 1.f / x;
#endif
}

// ---------------- prepass: fragment-order bf16 arrays + scaled norms + max partials ----
__global__ __launch_bounds__(256) void prepass4(const float* __restrict__ X,
                                                unsigned short* __restrict__ Kf,
                                                unsigned short* __restrict__ Vf,
                                                float* __restrict__ Norms,
                                                float* __restrict__ MaxPart) {
    __shared__ __align__(16) unsigned short sT[64 * LDS2];    // scaled [m][c]
    __shared__ __align__(16) unsigned short sVu[64 * LDS2];   // unscaled [c][m]
    __shared__ float sRed[4];
    const int b = blockIdx.y, m0 = blockIdx.x * 64;
    const float* Xb = X + (size_t)b * DIM * SEQ;
    const int t = threadIdx.x, w = t >> 6;
    const int mw = t & 15, cg = t >> 4;

    #pragma unroll
    for (int cr = 0; cr < 4; ++cr) {
        const int c = cg * 4 + cr;
        const f32x4 v = *(const f32x4*)(Xb + (size_t)c * SEQ + m0 + 4 * mw);
        *(ushort4*)(sVu + c * LDS2 + 4 * mw) =
            make_ushort4(f2bf(v.x), f2bf(v.y), f2bf(v.z), f2bf(v.w));
        sT[(4 * mw + 0) * LDS2 + c] = f2bf(v.x * QSCALE);
        sT[(4 * mw + 1) * LDS2 + c] = f2bf(v.y * QSCALE);
        sT[(4 * mw + 2) * LDS2 + c] = f2bf(v.z * QSCALE);
        sT[(4 * mw + 3) * LDS2 + c] = f2bf(v.w * QSCALE);
    }
    __syncthreads();
    const int m = t >> 2, ck = t & 3;   // Kf mapping: key row m, dim-chunk pair ck

    // ---- Kf: row m, dim-chunks 2ck and 2ck+1 ----
    const short8 a0 = *(const short8*)(sT + m * LDS2 + ck * 16);
    const short8 a1 = *(const short8*)(sT + m * LDS2 + ck * 16 + 8);
    {
        const size_t base = (size_t)b * 262144 + (size_t)(m0 >> 5) * 2048;  // shorts
        #pragma unroll
        for (int j = 0; j < 2; ++j) {
            const int chunk = 2 * ck + j;
            const int tile = m >> 5, mt = (m >> 4) & 1;
            const int quad = chunk & 3, ks = chunk >> 2;
            const size_t off = base + (size_t)(tile * 4 + mt * 2 + ks) * 512
                                    + (size_t)(quad * 16 + (m & 15)) * 8;
            *(short8*)(Kf + off) = j ? a1 : a0;
        }
    }
    // ---- scaled row norm (from a0/a1), exact C-S bound on scaled scores ----
    float s = 0.f;
    #pragma unroll
    for (int i = 0; i < 8; ++i) {
        const float f0 = bf2f((unsigned short)a0[i]);
        const float f1 = bf2f((unsigned short)a1[i]);
        s += f0 * f0 + f1 * f1;
    }
    s += __shfl_xor(s, 1);
    s += __shfl_xor(s, 2);
    const float nm = sqrtf(s);
    if (ck == 0) Norms[(size_t)b * SEQ + m0 + m] = nm;

    // ---- Vf: permuted B-frag order, one contiguous 16B fragment per (tile,ct,lane) ----
    // Thread t handles (ct, lane) = ((t>>6)&3, t&63) for both local tiles tl=0,1.
    // Element j of the fragment = sVu[(16ct+l15)*LDS2 + tl*32 + 16*(j>>2) + 4q + (j&3)]
    // -> two contiguous ushort4 gathers (j=0..3 and j=4..7).
    {
        const int ctv = (t >> 6) & 3, lv = t & 63;
        const int qv = lv >> 4, l15v = lv & 15;
        const int cidx = (16 * ctv + l15v) * LDS2;
        const size_t vbase = (size_t)b * 262144 + (size_t)(m0 >> 5) * 2048
                           + (size_t)ctv * 512 + (size_t)lv * 8;
        #pragma unroll
        for (int tl = 0; tl < 2; ++tl) {
            const ushort4 g0 = *(const ushort4*)(sVu + cidx + tl * 32 + 4 * qv);
            const ushort4 g1 = *(const ushort4*)(sVu + cidx + tl * 32 + 16 + 4 * qv);
            union { ushort4 g[2]; short8 v; } cat;
            cat.g[0] = g0; cat.g[1] = g1;
            *(short8*)(Vf + vbase + (size_t)tl * 2048) = cat.v;
        }
    }

    float mx = nm;
    #pragma unroll
    for (int d = 4; d < 64; d <<= 1) mx = fmaxf(mx, __shfl_xor(mx, d));
    if ((t & 63) == 0) sRed[w] = mx;
    __syncthreads();
    if (t == 0)
        MaxPart[b * 64 + blockIdx.x] =
            fmaxf(fmaxf(sRed[0], sRed[1]), fmaxf(sRed[2], sRed[3]));
}

// ---- per-iteration macros for the flash loop (kp/vp/qf/cin/acc_o/lp4 in scope) ----
#define LOADK(DST)                                                                 \
    {                                                                              \
        _Pragma("unroll")                                                          \
        for (int mt_ = 0; mt_ < 2; ++mt_) {                                        \
            _Pragma("unroll")                                                      \
            for (int ks_ = 0; ks_ < 2; ++ks_)                                      \
                DST[mt_][ks_] = *(const short8*)(kp + (mt_ * 2 + ks_) * 512);      \
        }                                                                          \
    }

#define LOADV(DST)                                                                 \
    {                                                                              \
        _Pragma("unroll")                                                          \
        for (int ct_ = 0; ct_ < 4; ++ct_)                                          \
            DST[ct_] = *(const short8*)(vp + ct_ * 512);                           \
    }

#define ATTN_STEP(KF, VF)                                                          \
    {                                                                              \
        f32x4 a_[2][2];                                                            \
        __builtin_amdgcn_s_setprio(1);                                             \
        _Pragma("unroll")                                                          \
        for (int qt_ = 0; qt_ < 2; ++qt_) {                                        \
            _Pragma("unroll")                                                      \
            for (int mt_ = 0; mt_ < 2; ++mt_) {                                    \
                f32x4 s_ = cin[qt_];                                               \
                s_ = __builtin_amdgcn_mfma_f32_16x16x32_bf16(KF[mt_][0], qf[qt_][0], s_, 0, 0, 0); \
                s_ = __builtin_amdgcn_mfma_f32_16x16x32_bf16(KF[mt_][1], qf[qt_][1], s_, 0, 0, 0); \
                a_[qt_][mt_] = s_;                                                 \
            }                                                                      \
        }                                                                          \
        __builtin_amdgcn_s_setprio(0);                                             \
        short8 pa_[2];                                                             \
        _Pragma("unroll")                                                          \
        for (int qt_ = 0; qt_ < 2; ++qt_) {                                        \
            union { unsigned u[4]; short8 v; } pk_;                                \
            _Pragma("unroll")                                                      \
            for (int mt_ = 0; mt_ < 2; ++mt_) {                                    \
                const float p0_ = fast_exp2(a_[qt_][mt_][0]);                      \
                const float p1_ = fast_exp2(a_[qt_][mt_][1]);                      \
                const float p2_ = fast_exp2(a_[qt_][mt_][2]);                      \
                const float p3_ = fast_exp2(a_[qt_][mt_][3]);                      \
                lp4[qt_] += (f32x4){p0_, p1_, p2_, p3_};                           \
                pk_.u[2 * mt_ + 0] = __builtin_amdgcn_perm(__float_as_uint(p1_), __float_as_uint(p0_), 0x07060302u); \
                pk_.u[2 * mt_ + 1] = __builtin_amdgcn_perm(__float_as_uint(p3_), __float_as_uint(p2_), 0x07060302u); \
            }                                                                      \
            pa_[qt_] = pk_.v;                                                      \
        }                                                                          \
        __builtin_amdgcn_s_setprio(1);                                             \
        _Pragma("unroll")                                                          \
        for (int qt_ = 0; qt_ < 2; ++qt_) {                                        \
            _Pragma("unroll")                                                      \
            for (int ct_ = 0; ct_ < 4; ++ct_)                                      \
                acc_o[qt_][ct_] = __builtin_amdgcn_mfma_f32_16x16x32_bf16(pa_[qt_], VF[ct_], acc_o[qt_][ct_], 0, 0, 0); \
        }                                                                          \
        __builtin_amdgcn_s_setprio(0);                                             \
    }

// BN=32 flash kernel, 2 waves x 32 Q rows, split-K x4. Fragment-order global K/V,
// LDS-free inner loop (P feeds PV directly from registers at K=32).
template <bool PARTIAL>
__global__ __launch_bounds__(128) void attn_split4(const unsigned short* __restrict__ Kf,
                                                   const unsigned short* __restrict__ Vf,
                                                   const float* __restrict__ Norms,
                                                   const float* __restrict__ MaxPart,
                                                   unsigned short* __restrict__ Obf,  // PARTIAL
                                                   float* __restrict__ Lbase,         // PARTIAL
                                                   float* __restrict__ Out,           // !PARTIAL
                                                   int niter) {
    __shared__ __align__(16) float sO[64 * LDO];   // epilogue staging only (17408 B)

    const int tid  = threadIdx.x;
    const int lane = tid & 63;
    const int w    = tid >> 6;
    const int l15  = lane & 15;
    const int quad = lane >> 4;

    const int b   = blockIdx.y;
    const int s0  = blockIdx.x * 64;
    const int h   = blockIdx.z;
    const int kt0 = h * niter;
    const unsigned short* Kfb = Kf + (size_t)b * 262144;
    const unsigned short* Vfb = Vf + (size_t)b * 262144;

    float mxn = MaxPart[b * 64 + lane];
    #pragma unroll
    for (int d = 1; d < 64; d <<= 1) mxn = fmaxf(mxn, __shfl_xor(mxn, d));

    // Q frags from Kf (scaled): row = s0+32w+16qt+l15 -> tile=(s0+32w)>>5, mt=qt
    short8 qf[2][2];
    f32x4 cin[2];
    const int qtile = (s0 + 32 * w) >> 5;
    #pragma unroll
    for (int qt = 0; qt < 2; ++qt) {
        #pragma unroll
        for (int ks = 0; ks < 2; ++ks)
            qf[qt][ks] = *(const short8*)(Kfb + (size_t)(qtile * 4 + qt * 2 + ks) * 512 + lane * 8);
        const float mrow = Norms[(size_t)b * SEQ + s0 + 32 * w + 16 * qt + l15] * mxn;
        cin[qt] = (f32x4){-mrow, -mrow, -mrow, -mrow};
    }

    f32x4 acc_o[2][4];
    #pragma unroll
    for (int qt = 0; qt < 2; ++qt)
        #pragma unroll
        for (int ct = 0; ct < 4; ++ct) acc_o[qt][ct] = (f32x4){0.f, 0.f, 0.f, 0.f};
    f32x4 lp4[2];
    lp4[0] = (f32x4){0.f, 0.f, 0.f, 0.f};
    lp4[1] = (f32x4){0.f, 0.f, 0.f, 0.f};

    // ---- fragment stream pointers (lane-contiguous 1KB per 16B-load) ----
    const unsigned short* kp = Kfb + (size_t)kt0 * 2048 + lane * 8;
    const unsigned short* vp = Vfb + (size_t)kt0 * 2048 + lane * 8;

    short8 kA[2][2], kB[2][2];
    LOADK(kA);
    kp += 2048;

    for (int it = 0; it < niter; it += 2) {
        short8 vfA[4];
        LOADV(vfA); vp += 2048;
        LOADK(kB);  kp += 2048;          // prefetch K for iter it+1
        ATTN_STEP(kA, vfA);

        short8 vfB[4];
        LOADV(vfB); vp += 2048;
        LOADK(kA);  kp += 2048;          // prefetch K for iter it+2; on the final pair this
                                         // over-reads <=2 tiles past the slab end -- still
                                         // inside d_ws (Vf/Norms regions), values unused.
        ATTN_STEP(kB, vfB);
    }

    float lp[2];
    #pragma unroll
    for (int qt = 0; qt < 2; ++qt) {
        lp[qt] = (lp4[qt][0] + lp4[qt][1]) + (lp4[qt][2] + lp4[qt][3]);
        lp[qt] += __shfl_xor(lp[qt], 16);
        lp[qt] += __shfl_xor(lp[qt], 32);
    }

    if (PARTIAL) {
        if (quad == 0) {
            #pragma unroll
            for (int qt = 0; qt < 2; ++qt)
                (Lbase + (size_t)h * 8 * SEQ)[(size_t)b * SEQ + s0 + 32 * w + 16 * qt + l15] = lp[qt];
        }
    } else {
        #pragma unroll
        for (int qt = 0; qt < 2; ++qt) {
            float inv[4];
            #pragma unroll
            for (int r = 0; r < 4; ++r) inv[r] = fast_rcp(__shfl(lp[qt], 4 * quad + r));
            #pragma unroll
            for (int ct = 0; ct < 4; ++ct)
                #pragma unroll
                for (int r = 0; r < 4; ++r) acc_o[qt][ct][r] *= inv[r];
        }
    }

    #pragma unroll
    for (int qt = 0; qt < 2; ++qt)
        #pragma unroll
        for (int ct = 0; ct < 4; ++ct) {
            const int c = 16 * ct + l15;
            #pragma unroll
            for (int r = 0; r < 4; ++r)
                sO[c * LDO + 32 * w + 16 * qt + 4 * quad + r] = acc_o[qt][ct][r];
        }
    __syncthreads();
    const int mw = tid & 15, cg = tid >> 4;
    if (PARTIAL) {
        unsigned short* Op = Obf + (size_t)h * 8 * DIM * SEQ;
        #pragma unroll
        for (int cc = 0; cc < 8; ++cc) {
            const int c = cg + 8 * cc;
            const f32x4 v = *(const f32x4*)(sO + c * LDO + 4 * mw);
            *(ushort4*)(Op + ((size_t)b * DIM + c) * SEQ + s0 + 4 * mw) =
                make_ushort4(f2bf(v.x), f2bf(v.y), f2bf(v.z), f2bf(v.w));
        }
    } else {
        #pragma unroll
        for (int cc = 0; cc < 8; ++cc) {
            const int c = cg + 8 * cc;
            const f32x4 v = *(const f32x4*)(sO + c * LDO + 4 * mw);
            *(f32x4*)(Out + ((size_t)b * DIM + c) * SEQ + s0 + 4 * mw) = v;
        }
    }
}

__global__ __launch_bounds__(256) void combine4(const unsigned short* __restrict__ Obf,
                                                const float* __restrict__ Lp,
                                                float* __restrict__ Out) {
    const int gid = blockIdx.x * 256 + threadIdx.x;
    const size_t base = (size_t)gid * 4;
    const int s = (int)(base & 4095);
    const int b = (int)(base >> 18);
    f32x4 os = (f32x4){0.f, 0.f, 0.f, 0.f};
    f32x4 ls = (f32x4){0.f, 0.f, 0.f, 0.f};
    #pragma unroll
    for (int h = 0; h < 4; ++h) {
        const ushort4 o = *(const ushort4*)(Obf + (size_t)h * 2097152 + base);
        os[0] += bf2f(o.x); os[1] += bf2f(o.y); os[2] += bf2f(o.z); os[3] += bf2f(o.w);
        const f32x4 l = *(const f32x4*)(Lp + (size_t)h * 8 * SEQ + b * SEQ + s);
        #pragma unroll
        for (int i = 0; i < 4; ++i) ls[i] += l[i];
    }
    f32x4 o;
    #pragma unroll
    for (int i = 0; i < 4; ++i) o[i] = os[i] / ls[i];
    *(f32x4*)(Out + base) = o;
}

__global__ __launch_bounds__(256, 2) void attn_fallback(const float* __restrict__ X,
                                                        float* __restrict__ Out) {
    __shared__ __align__(16) unsigned char smem[27648];
    unsigned short* sK = (unsigned short*)smem;
    unsigned short* sV = (unsigned short*)(smem + 9216);
    unsigned short* sP = (unsigned short*)(smem + 18432);
    float*          sO = (float*)smem;
    const int tid  = threadIdx.x;
    const int lane = tid & 63;
    const int w    = tid >> 6;
    const int l15  = lane & 15;
    const int quad = lane >> 4;
    const int b  = blockIdx.y;
    const int s0 = blockIdx.x * 64;
    const float* Xb = X + (size_t)b * DIM * SEQ;
    const int mgrp = tid & 15;
    const int c0   = tid >> 4;

    for (int cc = 0; cc < 4; ++cc) {
        int c = c0 + 16 * cc;
        const f32x4 v = *(const f32x4*)(Xb + (size_t)c * SEQ + s0 + 4 * mgrp);
        sK[(4 * mgrp + 0) * LDB + c] = f2bf(v.x);
        sK[(4 * mgrp + 1) * LDB + c] = f2bf(v.y);
        sK[(4 * mgrp + 2) * LDB + c] = f2bf(v.z);
        sK[(4 * mgrp + 3) * LDB + c] = f2bf(v.w);
    }
    __syncthreads();
    short8 qf0, qf1;
    {
        const int row = 16 * w + l15;
        qf0 = *(const short8*)(sK + row * LDB + quad * 8);
        qf1 = *(const short8*)(sK + row * LDB + 32 + quad * 8);
    }
    __syncthreads();
    f32x4 acc_o[4];
    for (int ct = 0; ct < 4; ++ct) acc_o[ct] = (f32x4){0.f, 0.f, 0.f, 0.f};
    float m_i[4] = {-1e30f, -1e30f, -1e30f, -1e30f};
    float l_i[4] = {0.f, 0.f, 0.f, 0.f};
    for (int kt = 0; kt < SEQ / 64; ++kt) {
        const int m0 = kt * 64;
        for (int cc = 0; cc < 4; ++cc) {
            int c = c0 + 16 * cc;
            const f32x4 v = *(const f32x4*)(Xb + (size_t)c * SEQ + m0 + 4 * mgrp);
            unsigned short h0 = f2bf(v.x), h1 = f2bf(v.y), h2 = f2bf(v.z), h3 = f2bf(v.w);
            *(ushort4*)(sV + c * LDB + 4 * mgrp) = make_ushort4(h0, h1, h2, h3);
            sK[(4 * mgrp + 0) * LDB + c] = h0;
            sK[(4 * mgrp + 1) * LDB + c] = h1;
            sK[(4 * mgrp + 2) * LDB + c] = h2;
            sK[(4 * mgrp + 3) * LDB + c] = h3;
        }
        __syncthreads();
        short8 vf[2][4];
        for (int ks = 0; ks < 2; ++ks)
            for (int ct = 0; ct < 4; ++ct)
                vf[ks][ct] = *(const short8*)(sV + (16 * ct + l15) * LDB + ks * 32 + quad * 8);
        f32x4 acc_s[4];
        for (int mt = 0; mt < 4; ++mt) {
            const int row = 16 * mt + l15;
            const short8 kf0 = *(const short8*)(sK + row * LDB + quad * 8);
            const short8 kf1 = *(const short8*)(sK + row * LDB + 32 + quad * 8);
            f32x4 a = (f32x4){0.f, 0.f, 0.f, 0.f};
            a = __builtin_amdgcn_mfma_f32_16x16x32_bf16(qf0, kf0, a, 0, 0, 0);
            a = __builtin_amdgcn_mfma_f32_16x16x32_bf16(qf1, kf1, a, 0, 0, 0);
            acc_s[mt] = a;
        }
        float alpha[4];
        for (int r = 0; r < 4; ++r) {
            float mx = fmaxf(fmaxf(acc_s[0][r], acc_s[1][r]), fmaxf(acc_s[2][r], acc_s[3][r]));
            mx = fmaxf(mx, __shfl_xor(mx, 1));
            mx = fmaxf(mx, __shfl_xor(mx, 2));
            mx = fmaxf(mx, __shfl_xor(mx, 4));
            mx = fmaxf(mx, __shfl_xor(mx, 8));
            const float mnew = fmaxf(m_i[r], mx);
            alpha[r] = __expf(m_i[r] - mnew);
            m_i[r] = mnew;
        }
        float rowsum[4] = {0.f, 0.f, 0.f, 0.f};
        unsigned short pb[4][4];
        for (int mt = 0; mt < 4; ++mt)
            for (int r = 0; r < 4; ++r) {
                const float p = __expf(acc_s[mt][r] - m_i[r]);
                rowsum[r] += p;
                pb[mt][r] = f2bf(p);
            }
        for (int r = 0; r < 4; ++r) {
            float s = rowsum[r];
            s += __shfl_xor(s, 1);
            s += __shfl_xor(s, 2);
            s += __shfl_xor(s, 4);
            s += __shfl_xor(s, 8);
            l_i[r] = alpha[r] * l_i[r] + s;
        }
        for (int ct = 0; ct < 4; ++ct)
            for (int r = 0; r < 4; ++r)
                acc_o[ct][r] *= alpha[r];
        for (int mt = 0; mt < 4; ++mt)
            for (int r = 0; r < 4; ++r)
                sP[(16 * w + quad * 4 + r) * LDB + l15 + 16 * mt] = pb[mt][r];
        __syncthreads();
        const short8 pf0 = *(const short8*)(sP + (16 * w + l15) * LDB + quad * 8);
        const short8 pf1 = *(const short8*)(sP + (16 * w + l15) * LDB + 32 + quad * 8);
        for (int ct = 0; ct < 4; ++ct) {
            acc_o[ct] = __builtin_amdgcn_mfma_f32_16x16x32_bf16(pf0, vf[0][ct], acc_o[ct], 0, 0, 0);
            acc_o[ct] = __builtin_amdgcn_mfma_f32_16x16x32_bf16(pf1, vf[1][ct], acc_o[ct], 0, 0, 0);
        }
    }
    float inv[4];
    for (int r = 0; r < 4; ++r) inv[r] = 1.f / l_i[r];
    for (int ct = 0; ct < 4; ++ct) {
        const int c = 16 * ct + l15;
        for (int r = 0; r < 4; ++r)
            sO[c * LDO + 16 * w + quad * 4 + r] = acc_o[ct][r] * inv[r];
    }
    __syncthreads();
    for (int cc = 0; cc < 4; ++cc) {
        const int c = c0 + 16 * cc;
        const f32x4 v = *(const f32x4*)(sO + c * LDO + 4 * mgrp);
        *(f32x4*)(Out + (size_t)b * DIM * SEQ + (size_t)c * SEQ + s0 + 4 * mgrp) = v;
    }
}

extern "C" void kernel_launch(void* const* d_in, const int* in_sizes, int n_in,
                              void* d_out, int out_size, void* d_ws, size_t ws_size,
                              hipStream_t stream) {
    const float* X = (const float*)d_in[0];
    float* Out = (float*)d_out;
    const size_t elems = (size_t)8 * SEQ * DIM;               // 2M
    const size_t offVf    = elems * 2;                        // Kf 4MB
    const size_t offNorms = offVf + elems * 2;                // Vf 4MB -> 8MB
    const size_t offMaxP  = offNorms + (size_t)8 * SEQ * 4;   // +128KB
    const size_t offObf   = offMaxP + 8 * 64 * 4;             // +2KB
    const size_t offLp    = offObf + 4 * elems * 2;           // +16MB (4 bf16 slabs)
    const size_t need     = offLp + 4 * (size_t)8 * SEQ * 4;  // ~24.64MB (proven budget)

    if (ws_size >= need) {
        unsigned short* Kf = (unsigned short*)d_ws;
        unsigned short* Vf = (unsigned short*)((char*)d_ws + offVf);
        float* Norms   = (float*)((char*)d_ws + offNorms);
        float* MaxPart = (float*)((char*)d_ws + offMaxP);
        unsigned short* Obf = (unsigned short*)((char*)d_ws + offObf);
        float* Lp = (float*)((char*)d_ws + offLp);
        prepass4<<<dim3(64, 8), 256, 0, stream>>>(X, Kf, Vf, Norms, MaxPart);
        attn_split4<true><<<dim3(64, 8, 4), 128, 0, stream>>>(Kf, Vf, Norms, MaxPart,
                                                              Obf, Lp, nullptr, 32);
        combine4<<<(int)(elems / 1024), 256, 0, stream>>>(Obf, Lp, Out);
    } else {
        attn_fallback<<<dim3(64, 8), 256, 0, stream>>>(X, Out);
    }
}

// Round 3
// 105.732 us; speedup vs baseline: 1.2390x; 1.1211x over previous
//
#include <hip/hip_runtime.h>
#include <math.h>

// Non-local attention: X [8, 64, 64, 64] fp32.
// Per batch b: Q=K=V = X_b^T  [S=4096, D=64];  out = softmax(Q K^T) V, stored [b][c][s].
//
// R13: arithmetic-intensity + XCD-locality round. R12 was bandwidth-bound below HBM:
// 1.07 GB of K/V fragment stream vs ~20 TB/s effective (round-robin blocks force every
// XCD to touch all 8 batches' slabs = 8MB > 4MB L2, so traffic spills to L3).
//   (a) Each wave now owns 64 Q rows (qt=0..3): the same 8KB/iter K/V stream feeds
//       32 MFMAs instead of 16 -> stream halves to 535 MB.
//   (b) XCD-pinned batch remap: dispatch is round-robin by linear wg id, so b = gid&7
//       puts each batch's 1MB K/V slab on exactly one XCD -> L2-resident stream.
//       (Pure work remap -- correctness never depends on placement.)
//   (c) s_setprio dropped: it fenced the scheduler between S/exp/PV phases; with
//       2 waves/SIMD we want intra-wave MFMA||VALU overlap.
// Zero-movement P retained from R12: with k-slot<->key bijection  q*8+j <-> 16*(j>>2)+4q+(j&3),
// the PV A-fragment is the lane's OWN 8 exp'd scores (bf16-packed in regs) and Vf is
// pre-laid-out in that permuted order (one lane-contiguous 16B load per fragment).
// K register double-buffered one tile ahead; V loaded at iter top, consumed after S+exp.
// Split-K x4, raw v_exp_f32 softmax with Cauchy-Schwarz bound folded into MFMA C-init.
//
// Kf[b][tile][mt][ks][lane]: scaled bf16, lane(=quad*16+l15) holds
//   XbfT_scaled[tile*32+mt*16+l15][quad*8+32*ks .. +8]   (also serves Q fragments)
// Vf[b][tile][ct][lane][j]: unscaled bf16, element j at lane (l15,q) holds
//   XbfT[tile*32 + 16*(j>>2) + 4*q + (j&3)][16*ct + l15]   (permuted B-frag order)

#define SEQ 4096
#define DIM 64
#define LDB 72
#define LDO 68
#define LDO2 133
#define LDS2 68
#define QSCALE 1.2011224087864498f   // sqrt(log2(e))

typedef __attribute__((ext_vector_type(8))) short  short8;
typedef __attribute__((ext_vector_type(4))) float  f32x4;

__device__ __forceinline__ unsigned short f2bf(float f) {
    union { float f; unsigned int u; } x; x.f = f;
    unsigned int u = x.u + 0x7FFFu + ((x.u >> 16) & 1u);
    return (unsigned short)(u >> 16);
}
__device__ __forceinline__ float bf2f(unsigned short h) {
    union { unsigned int u; float f; } x; x.u = ((unsigned int)h) << 16; return x.f;
}
__device__ __forceinline__ float fast_exp2(float x) {
#if __has_builtin(__builtin_amdgcn_exp2f)
    return __builtin_amdgcn_exp2f(x);
#else
    float r;
    asm("v_exp_f32 %0, %1\n\ts_nop 0" : "=v"(r) : "v"(x));
    return r;
#endif
}
__device__ __forceinline__ float fast_rcp(float x) {
#if __has_builtin(__builtin_amdgcn_rcpf)
    return __builtin_amdgcn_rcpf(x);
#else
    return 1.f / x;
#endif
}

// ---------------- prepass: fragment-order bf16 arrays + scaled norms + max partials ----
__global__ __launch_bounds__(256) void prepass4(const float* __restrict__ X,
                                                unsigned short* __restrict__ Kf,
                                                unsigned short* __restrict__ Vf,
                                                float* __restrict__ Norms,
                                                float* __restrict__ MaxPart) {
    __shared__ __align__(16) unsigned short sT[64 * LDS2];    // scaled [m][c]
    __shared__ __align__(16) unsigned short sVu[64 * LDS2];   // unscaled [c][m]
    __shared__ float sRed[4];
    const int b = blockIdx.y, m0 = blockIdx.x * 64;
    const float* Xb = X + (size_t)b * DIM * SEQ;
    const int t = threadIdx.x, w = t >> 6;
    const int mw = t & 15, cg = t >> 4;

    #pragma unroll
    for (int cr = 0; cr < 4; ++cr) {
        const int c = cg * 4 + cr;
        const f32x4 v = *(const f32x4*)(Xb + (size_t)c * SEQ + m0 + 4 * mw);
        *(ushort4*)(sVu + c * LDS2 + 4 * mw) =
            make_ushort4(f2bf(v.x), f2bf(v.y), f2bf(v.z), f2bf(v.w));
        sT[(4 * mw + 0) * LDS2 + c] = f2bf(v.x * QSCALE);
        sT[(4 * mw + 1) * LDS2 + c] = f2bf(v.y * QSCALE);
        sT[(4 * mw + 2) * LDS2 + c] = f2bf(v.z * QSCALE);
        sT[(4 * mw + 3) * LDS2 + c] = f2bf(v.w * QSCALE);
    }
    __syncthreads();
    const int m = t >> 2, ck = t & 3;   // Kf mapping: key row m, dim-chunk pair ck

    // ---- Kf: row m, dim-chunks 2ck and 2ck+1 ----
    const short8 a0 = *(const short8*)(sT + m * LDS2 + ck * 16);
    const short8 a1 = *(const short8*)(sT + m * LDS2 + ck * 16 + 8);
    {
        const size_t base = (size_t)b * 262144 + (size_t)(m0 >> 5) * 2048;  // shorts
        #pragma unroll
        for (int j = 0; j < 2; ++j) {
            const int chunk = 2 * ck + j;
            const int tile = m >> 5, mt = (m >> 4) & 1;
            const int quad = chunk & 3, ks = chunk >> 2;
            const size_t off = base + (size_t)(tile * 4 + mt * 2 + ks) * 512
                                    + (size_t)(quad * 16 + (m & 15)) * 8;
            *(short8*)(Kf + off) = j ? a1 : a0;
        }
    }
    // ---- scaled row norm (from a0/a1), exact C-S bound on scaled scores ----
    float s = 0.f;
    #pragma unroll
    for (int i = 0; i < 8; ++i) {
        const float f0 = bf2f((unsigned short)a0[i]);
        const float f1 = bf2f((unsigned short)a1[i]);
        s += f0 * f0 + f1 * f1;
    }
    s += __shfl_xor(s, 1);
    s += __shfl_xor(s, 2);
    const float nm = sqrtf(s);
    if (ck == 0) Norms[(size_t)b * SEQ + m0 + m] = nm;

    // ---- Vf: permuted B-frag order, one contiguous 16B fragment per (tile,ct,lane) ----
    {
        const int ctv = (t >> 6) & 3, lv = t & 63;
        const int qv = lv >> 4, l15v = lv & 15;
        const int cidx = (16 * ctv + l15v) * LDS2;
        const size_t vbase = (size_t)b * 262144 + (size_t)(m0 >> 5) * 2048
                           + (size_t)ctv * 512 + (size_t)lv * 8;
        #pragma unroll
        for (int tl = 0; tl < 2; ++tl) {
            const ushort4 g0 = *(const ushort4*)(sVu + cidx + tl * 32 + 4 * qv);
            const ushort4 g1 = *(const ushort4*)(sVu + cidx + tl * 32 + 16 + 4 * qv);
            union { ushort4 g[2]; short8 v; } cat;
            cat.g[0] = g0; cat.g[1] = g1;
            *(short8*)(Vf + vbase + (size_t)tl * 2048) = cat.v;
        }
    }

    float mx = nm;
    #pragma unroll
    for (int d = 4; d < 64; d <<= 1) mx = fmaxf(mx, __shfl_xor(mx, d));
    if ((t & 63) == 0) sRed[w] = mx;
    __syncthreads();
    if (t == 0)
        MaxPart[b * 64 + blockIdx.x] =
            fmaxf(fmaxf(sRed[0], sRed[1]), fmaxf(sRed[2], sRed[3]));
}

// ---- per-iteration macros for the flash loop (kp/vp/qf/cin/acc_o/lp4 in scope) ----
#define LOADK(DST)                                                                 \
    {                                                                              \
        _Pragma("unroll")                                                          \
        for (int mt_ = 0; mt_ < 2; ++mt_) {                                        \
            _Pragma("unroll")                                                      \
            for (int ks_ = 0; ks_ < 2; ++ks_)                                      \
                DST[mt_][ks_] = *(const short8*)(kp + (mt_ * 2 + ks_) * 512);      \
        }                                                                          \
    }

#define LOADV(DST)                                                                 \
    {                                                                              \
        _Pragma("unroll")                                                          \
        for (int ct_ = 0; ct_ < 4; ++ct_)                                          \
            DST[ct_] = *(const short8*)(vp + ct_ * 512);                           \
    }

#define ATTN_STEP(KF, VF)                                                          \
    {                                                                              \
        f32x4 a_[4][2];                                                            \
        _Pragma("unroll")                                                          \
        for (int qt_ = 0; qt_ < 4; ++qt_) {                                        \
            _Pragma("unroll")                                                      \
            for (int mt_ = 0; mt_ < 2; ++mt_) {                                    \
                f32x4 s_ = cin[qt_];                                               \
                s_ = __builtin_amdgcn_mfma_f32_16x16x32_bf16(KF[mt_][0], qf[qt_][0], s_, 0, 0, 0); \
                s_ = __builtin_amdgcn_mfma_f32_16x16x32_bf16(KF[mt_][1], qf[qt_][1], s_, 0, 0, 0); \
                a_[qt_][mt_] = s_;                                                 \
            }                                                                      \
        }                                                                          \
        short8 pa_[4];                                                             \
        _Pragma("unroll")                                                          \
        for (int qt_ = 0; qt_ < 4; ++qt_) {                                        \
            union { unsigned u[4]; short8 v; } pk_;                                \
            _Pragma("unroll")                                                      \
            for (int mt_ = 0; mt_ < 2; ++mt_) {                                    \
                const float p0_ = fast_exp2(a_[qt_][mt_][0]);                      \
                const float p1_ = fast_exp2(a_[qt_][mt_][1]);                      \
                const float p2_ = fast_exp2(a_[qt_][mt_][2]);                      \
                const float p3_ = fast_exp2(a_[qt_][mt_][3]);                      \
                lp4[qt_] += (f32x4){p0_, p1_, p2_, p3_};                           \
                pk_.u[2 * mt_ + 0] = __builtin_amdgcn_perm(__float_as_uint(p1_), __float_as_uint(p0_), 0x07060302u); \
                pk_.u[2 * mt_ + 1] = __builtin_amdgcn_perm(__float_as_uint(p3_), __float_as_uint(p2_), 0x07060302u); \
            }                                                                      \
            pa_[qt_] = pk_.v;                                                      \
        }                                                                          \
        _Pragma("unroll")                                                          \
        for (int qt_ = 0; qt_ < 4; ++qt_) {                                        \
            _Pragma("unroll")                                                      \
            for (int ct_ = 0; ct_ < 4; ++ct_)                                      \
                acc_o[qt_][ct_] = __builtin_amdgcn_mfma_f32_16x16x32_bf16(pa_[qt_], VF[ct_], acc_o[qt_][ct_], 0, 0, 0); \
        }                                                                          \
    }

// BN=32 flash kernel, 2 waves x 64 Q rows, split-K x4. Fragment-order global K/V,
// LDS-free inner loop (P feeds PV directly from registers at K=32).
template <bool PARTIAL>
__global__ __launch_bounds__(128, 2) void attn_split4(const unsigned short* __restrict__ Kf,
                                                      const unsigned short* __restrict__ Vf,
                                                      const float* __restrict__ Norms,
                                                      const float* __restrict__ MaxPart,
                                                      unsigned short* __restrict__ Obf,  // PARTIAL
                                                      float* __restrict__ Lbase,         // PARTIAL
                                                      float* __restrict__ Out,           // !PARTIAL
                                                      int niter) {
    __shared__ __align__(16) float sO[64 * LDO2];   // epilogue staging only (34048 B)

    const int tid  = threadIdx.x;
    const int lane = tid & 63;
    const int w    = tid >> 6;
    const int l15  = lane & 15;
    const int quad = lane >> 4;

    // XCD-pinned work remap: dispatch round-robins linear wg id across the 8 XCDs,
    // so gid&7 == XCD. Assign batch = gid&7 so each XCD streams exactly one batch's
    // 1MB K/V slab (L2-resident). Pure work remap -- placement only affects speed.
    const int gid  = blockIdx.x + 32 * (blockIdx.y + 8 * blockIdx.z);
    const int b    = gid & 7;
    const int rest = gid >> 3;             // 0..127
    const int s0   = (rest & 31) * 128;    // 128 Q rows per block
    const int h    = rest >> 5;            // 0..3 split-K quarter
    const int kt0  = h * niter;
    const unsigned short* Kfb = Kf + (size_t)b * 262144;
    const unsigned short* Vfb = Vf + (size_t)b * 262144;

    float mxn = MaxPart[b * 64 + lane];
    #pragma unroll
    for (int d = 1; d < 64; d <<= 1) mxn = fmaxf(mxn, __shfl_xor(mxn, d));

    // Q frags from Kf (scaled): wave w owns rows s0+64w .. +63 (qt = 0..3)
    short8 qf[4][2];
    f32x4 cin[4];
    const int qtile = (s0 + 64 * w) >> 5;
    #pragma unroll
    for (int qt = 0; qt < 4; ++qt) {
        #pragma unroll
        for (int ks = 0; ks < 2; ++ks)
            qf[qt][ks] = *(const short8*)(Kfb
                + (size_t)((qtile + (qt >> 1)) * 4 + (qt & 1) * 2 + ks) * 512 + lane * 8);
        const float mrow = Norms[(size_t)b * SEQ + s0 + 64 * w + 16 * qt + l15] * mxn;
        cin[qt] = (f32x4){-mrow, -mrow, -mrow, -mrow};
    }

    f32x4 acc_o[4][4];
    #pragma unroll
    for (int qt = 0; qt < 4; ++qt)
        #pragma unroll
        for (int ct = 0; ct < 4; ++ct) acc_o[qt][ct] = (f32x4){0.f, 0.f, 0.f, 0.f};
    f32x4 lp4[4];
    #pragma unroll
    for (int qt = 0; qt < 4; ++qt) lp4[qt] = (f32x4){0.f, 0.f, 0.f, 0.f};

    // ---- fragment stream pointers (lane-contiguous 1KB per 16B-load) ----
    const unsigned short* kp = Kfb + (size_t)kt0 * 2048 + lane * 8;
    const unsigned short* vp = Vfb + (size_t)kt0 * 2048 + lane * 8;

    short8 kA[2][2], kB[2][2];
    LOADK(kA);
    kp += 2048;

    for (int it = 0; it < niter; it += 2) {
        short8 vfA[4];
        LOADV(vfA); vp += 2048;
        LOADK(kB);  kp += 2048;          // prefetch K for iter it+1
        ATTN_STEP(kA, vfA);

        short8 vfB[4];
        LOADV(vfB); vp += 2048;
        LOADK(kA);  kp += 2048;          // prefetch K for iter it+2; final pair over-reads
                                         // <=2 tiles past the slab end -- still inside
                                         // d_ws (Vf/Norms regions), values unused.
        ATTN_STEP(kB, vfB);
    }

    float lp[4];
    #pragma unroll
    for (int qt = 0; qt < 4; ++qt) {
        lp[qt] = (lp4[qt][0] + lp4[qt][1]) + (lp4[qt][2] + lp4[qt][3]);
        lp[qt] += __shfl_xor(lp[qt], 16);
        lp[qt] += __shfl_xor(lp[qt], 32);
    }

    if (PARTIAL) {
        if (quad == 0) {
            #pragma unroll
            for (int qt = 0; qt < 4; ++qt)
                (Lbase + (size_t)h * 8 * SEQ)[(size_t)b * SEQ + s0 + 64 * w + 16 * qt + l15] = lp[qt];
        }
    } else {
        #pragma unroll
        for (int qt = 0; qt < 4; ++qt) {
            float inv[4];
            #pragma unroll
            for (int r = 0; r < 4; ++r) inv[r] = fast_rcp(__shfl(lp[qt], 4 * quad + r));
            #pragma unroll
            for (int ct = 0; ct < 4; ++ct)
                #pragma unroll
                for (int r = 0; r < 4; ++r) acc_o[qt][ct][r] *= inv[r];
        }
    }

    #pragma unroll
    for (int qt = 0; qt < 4; ++qt)
        #pragma unroll
        for (int ct = 0; ct < 4; ++ct) {
            const int c = 16 * ct + l15;
            #pragma unroll
            for (int r = 0; r < 4; ++r)
                sO[c * LDO2 + 64 * w + 16 * qt + 4 * quad + r] = acc_o[qt][ct][r];
        }
    __syncthreads();
    const int mw = tid & 31, cg = tid >> 5;   // mw: s-chunk (4 wide), cg: 0..3
    if (PARTIAL) {
        unsigned short* Op = Obf + (size_t)h * 8 * DIM * SEQ;
        #pragma unroll
        for (int cc = 0; cc < 16; ++cc) {
            const int c = cg + 4 * cc;
            const f32x4 v = *(const f32x4*)(sO + c * LDO2 + 4 * mw);
            *(ushort4*)(Op + ((size_t)b * DIM + c) * SEQ + s0 + 4 * mw) =
                make_ushort4(f2bf(v.x), f2bf(v.y), f2bf(v.z), f2bf(v.w));
        }
    } else {
        #pragma unroll
        for (int cc = 0; cc < 16; ++cc) {
            const int c = cg + 4 * cc;
            const f32x4 v = *(const f32x4*)(sO + c * LDO2 + 4 * mw);
            *(f32x4*)(Out + ((size_t)b * DIM + c) * SEQ + s0 + 4 * mw) = v;
        }
    }
}

__global__ __launch_bounds__(256) void combine4(const unsigned short* __restrict__ Obf,
                                                const float* __restrict__ Lp,
                                                float* __restrict__ Out) {
    const int gid = blockIdx.x * 256 + threadIdx.x;
    const size_t base = (size_t)gid * 4;
    const int s = (int)(base & 4095);
    const int b = (int)(base >> 18);
    f32x4 os = (f32x4){0.f, 0.f, 0.f, 0.f};
    f32x4 ls = (f32x4){0.f, 0.f, 0.f, 0.f};
    #pragma unroll
    for (int h = 0; h < 4; ++h) {
        const ushort4 o = *(const ushort4*)(Obf + (size_t)h * 2097152 + base);
        os[0] += bf2f(o.x); os[1] += bf2f(o.y); os[2] += bf2f(o.z); os[3] += bf2f(o.w);
        const f32x4 l = *(const f32x4*)(Lp + (size_t)h * 8 * SEQ + b * SEQ + s);
        #pragma unroll
        for (int i = 0; i < 4; ++i) ls[i] += l[i];
    }
    f32x4 o;
    #pragma unroll
    for (int i = 0; i < 4; ++i) o[i] = os[i] / ls[i];
    *(f32x4*)(Out + base) = o;
}

__global__ __launch_bounds__(256, 2) void attn_fallback(const float* __restrict__ X,
                                                        float* __restrict__ Out) {
    __shared__ __align__(16) unsigned char smem[27648];
    unsigned short* sK = (unsigned short*)smem;
    unsigned short* sV = (unsigned short*)(smem + 9216);
    unsigned short* sP = (unsigned short*)(smem + 18432);
    float*          sO = (float*)smem;
    const int tid  = threadIdx.x;
    const int lane = tid & 63;
    const int w    = tid >> 6;
    const int l15  = lane & 15;
    const int quad = lane >> 4;
    const int b  = blockIdx.y;
    const int s0 = blockIdx.x * 64;
    const float* Xb = X + (size_t)b * DIM * SEQ;
    const int mgrp = tid & 15;
    const int c0   = tid >> 4;

    for (int cc = 0; cc < 4; ++cc) {
        int c = c0 + 16 * cc;
        const f32x4 v = *(const f32x4*)(Xb + (size_t)c * SEQ + s0 + 4 * mgrp);
        sK[(4 * mgrp + 0) * LDB + c] = f2bf(v.x);
        sK[(4 * mgrp + 1) * LDB + c] = f2bf(v.y);
        sK[(4 * mgrp + 2) * LDB + c] = f2bf(v.z);
        sK[(4 * mgrp + 3) * LDB + c] = f2bf(v.w);
    }
    __syncthreads();
    short8 qf0, qf1;
    {
        const int row = 16 * w + l15;
        qf0 = *(const short8*)(sK + row * LDB + quad * 8);
        qf1 = *(const short8*)(sK + row * LDB + 32 + quad * 8);
    }
    __syncthreads();
    f32x4 acc_o[4];
    for (int ct = 0; ct < 4; ++ct) acc_o[ct] = (f32x4){0.f, 0.f, 0.f, 0.f};
    float m_i[4] = {-1e30f, -1e30f, -1e30f, -1e30f};
    float l_i[4] = {0.f, 0.f, 0.f, 0.f};
    for (int kt = 0; kt < SEQ / 64; ++kt) {
        const int m0 = kt * 64;
        for (int cc = 0; cc < 4; ++cc) {
            int c = c0 + 16 * cc;
            const f32x4 v = *(const f32x4*)(Xb + (size_t)c * SEQ + m0 + 4 * mgrp);
            unsigned short h0 = f2bf(v.x), h1 = f2bf(v.y), h2 = f2bf(v.z), h3 = f2bf(v.w);
            *(ushort4*)(sV + c * LDB + 4 * mgrp) = make_ushort4(h0, h1, h2, h3);
            sK[(4 * mgrp + 0) * LDB + c] = h0;
            sK[(4 * mgrp + 1) * LDB + c] = h1;
            sK[(4 * mgrp + 2) * LDB + c] = h2;
            sK[(4 * mgrp + 3) * LDB + c] = h3;
        }
        __syncthreads();
        short8 vf[2][4];
        for (int ks = 0; ks < 2; ++ks)
            for (int ct = 0; ct < 4; ++ct)
                vf[ks][ct] = *(const short8*)(sV + (16 * ct + l15) * LDB + ks * 32 + quad * 8);
        f32x4 acc_s[4];
        for (int mt = 0; mt < 4; ++mt) {
            const int row = 16 * mt + l15;
            const short8 kf0 = *(const short8*)(sK + row * LDB + quad * 8);
            const short8 kf1 = *(const short8*)(sK + row * LDB + 32 + quad * 8);
            f32x4 a = (f32x4){0.f, 0.f, 0.f, 0.f};
            a = __builtin_amdgcn_mfma_f32_16x16x32_bf16(qf0, kf0, a, 0, 0, 0);
            a = __builtin_amdgcn_mfma_f32_16x16x32_bf16(qf1, kf1, a, 0, 0, 0);
            acc_s[mt] = a;
        }
        float alpha[4];
        for (int r = 0; r < 4; ++r) {
            float mx = fmaxf(fmaxf(acc_s[0][r], acc_s[1][r]), fmaxf(acc_s[2][r], acc_s[3][r]));
            mx = fmaxf(mx, __shfl_xor(mx, 1));
            mx = fmaxf(mx, __shfl_xor(mx, 2));
            mx = fmaxf(mx, __shfl_xor(mx, 4));
            mx = fmaxf(mx, __shfl_xor(mx, 8));
            const float mnew = fmaxf(m_i[r], mx);
            alpha[r] = __expf(m_i[r] - mnew);
            m_i[r] = mnew;
        }
        float rowsum[4] = {0.f, 0.f, 0.f, 0.f};
        unsigned short pb[4][4];
        for (int mt = 0; mt < 4; ++mt)
            for (int r = 0; r < 4; ++r) {
                const float p = __expf(acc_s[mt][r] - m_i[r]);
                rowsum[r] += p;
                pb[mt][r] = f2bf(p);
            }
        for (int r = 0; r < 4; ++r) {
            float s = rowsum[r];
            s += __shfl_xor(s, 1);
            s += __shfl_xor(s, 2);
            s += __shfl_xor(s, 4);
            s += __shfl_xor(s, 8);
            l_i[r] = alpha[r] * l_i[r] + s;
        }
        for (int ct = 0; ct < 4; ++ct)
            for (int r = 0; r < 4; ++r)
                acc_o[ct][r] *= alpha[r];
        for (int mt = 0; mt < 4; ++mt)
            for (int r = 0; r < 4; ++r)
                sP[(16 * w + quad * 4 + r) * LDB + l15 + 16 * mt] = pb[mt][r];
        __syncthreads();
        const short8 pf0 = *(const short8*)(sP + (16 * w + l15) * LDB + quad * 8);
        const short8 pf1 = *(const short8*)(sP + (16 * w + l15) * LDB + 32 + quad * 8);
        for (int ct = 0; ct < 4; ++ct) {
            acc_o[ct] = __builtin_amdgcn_mfma_f32_16x16x32_bf16(pf0, vf[0][ct], acc_o[ct], 0, 0, 0);
            acc_o[ct] = __builtin_amdgcn_mfma_f32_16x16x32_bf16(pf1, vf[1][ct], acc_o[ct], 0, 0, 0);
        }
    }
    float inv[4];
    for (int r = 0; r < 4; ++r) inv[r] = 1.f / l_i[r];
    for (int ct = 0; ct < 4; ++ct) {
        const int c = 16 * ct + l15;
        for (int r = 0; r < 4; ++r)
            sO[c * LDO + 16 * w + quad * 4 + r] = acc_o[ct][r] * inv[r];
    }
    __syncthreads();
    for (int cc = 0; cc < 4; ++cc) {
        const int c = c0 + 16 * cc;
        const f32x4 v = *(const f32x4*)(sO + c * LDO + 4 * mgrp);
        *(f32x4*)(Out + (size_t)b * DIM * SEQ + (size_t)c * SEQ + s0 + 4 * mgrp) = v;
    }
}

extern "C" void kernel_launch(void* const* d_in, const int* in_sizes, int n_in,
                              void* d_out, int out_size, void* d_ws, size_t ws_size,
                              hipStream_t stream) {
    const float* X = (const float*)d_in[0];
    float* Out = (float*)d_out;
    const size_t elems = (size_t)8 * SEQ * DIM;               // 2M
    const size_t offVf    = elems * 2;                        // Kf 4MB
    const size_t offNorms = offVf + elems * 2;                // Vf 4MB -> 8MB
    const size_t offMaxP  = offNorms + (size_t)8 * SEQ * 4;   // +128KB
    const size_t offObf   = offMaxP + 8 * 64 * 4;             // +2KB
    const size_t offLp    = offObf + 4 * elems * 2;           // +16MB (4 bf16 slabs)
    const size_t need     = offLp + 4 * (size_t)8 * SEQ * 4;  // ~24.64MB (proven budget)

    if (ws_size >= need) {
        unsigned short* Kf = (unsigned short*)d_ws;
        unsigned short* Vf = (unsigned short*)((char*)d_ws + offVf);
        float* Norms   = (float*)((char*)d_ws + offNorms);
        float* MaxPart = (float*)((char*)d_ws + offMaxP);
        unsigned short* Obf = (unsigned short*)((char*)d_ws + offObf);
        float* Lp = (float*)((char*)d_ws + offLp);
        prepass4<<<dim3(64, 8), 256, 0, stream>>>(X, Kf, Vf, Norms, MaxPart);
        attn_split4<true><<<dim3(32, 8, 4), 128, 0, stream>>>(Kf, Vf, Norms, MaxPart,
                                                              Obf, Lp, nullptr, 32);
        combine4<<<(int)(elems / 1024), 256, 0, stream>>>(Obf, Lp, Out);
    } else {
        attn_fallback<<<dim3(64, 8), 256, 0, stream>>>(X, Out);
    }
}